// Round 18
// baseline (101.099 us; speedup 1.0000x reference)
//
#include <hip/hip_runtime.h>
#include <cmath>

#define T_TOKENS 16384
#define DIM 2048
#define NG 4
#define EPG 16
#define NE 64
#define NJ2 68          // 4 group + 64 expert rows (complexity MLP dead: k==1 always)
#define NT2 5           // n-tiles of 16 (80 padded)
#define NJP2 80
#define BM 64           // tokens per gemm block
#define KS 4            // K-split
#define KSL (DIM / KS)  // 512
#define NITER (KSL / 32)  // 16
#define TAU 0.02f

#define XBUF_B 8192     // 64 tok * 32 f * 4B per iter
#define WBUF_B 5120     // 5 cells * 1KB

typedef __attribute__((ext_vector_type(8))) short bf16x8;
typedef __attribute__((ext_vector_type(4))) float f32x4;

// ws float-offsets
#define WF_FLOATS (64 * NT2 * 64 * 4)             // 81920 floats
#define P_OFF WF_FLOATS
#define P_FLOATS ((size_t)KS * T_TOKENS * NJP2)   // 5.24M floats (21 MB)
#define SUM_OFF (P_OFF + P_FLOATS)

static __device__ inline unsigned bf16rne(float x) {
    unsigned u = __float_as_uint(x);
    return (u + 0x7FFFu + ((u >> 16) & 1u)) >> 16;
}

#define GLOAD_LDS(gsrc, ldst) \
    __builtin_amdgcn_global_load_lds( \
        (const __attribute__((address_space(1))) void*)(gsrc), \
        (__attribute__((address_space(3))) void*)(ldst), 16, 0, 0)

// Fragment-linear bf16 weights: [kstep 64][tile 5][lane 64][16B].
__global__ void moe_prep(const float* __restrict__ Wg, const float* __restrict__ We,
                         float* __restrict__ ws, float* __restrict__ sums) {
    int bid = blockIdx.x;                 // 320
    int kstep = bid / NT2, nt = bid % NT2;
    int lane = threadIdx.x;
    if (bid == 0) { sums[lane] = 0.f; sums[64 + lane] = 0.f; }
    int row = nt * 16 + (lane & 15);
    int k0 = kstep * 32 + (lane >> 4) * 8;
    const float* src = nullptr;
    if (row < NG)        src = Wg + (size_t)row * DIM;
    else if (row < NJ2)  src = We + (size_t)(row - NG) * DIM;
    unsigned r0 = 0, r1 = 0, r2 = 0, r3 = 0;
    if (src) {
        r0 = bf16rne(src[k0 + 0]) | (bf16rne(src[k0 + 1]) << 16);
        r1 = bf16rne(src[k0 + 2]) | (bf16rne(src[k0 + 3]) << 16);
        r2 = bf16rne(src[k0 + 4]) | (bf16rne(src[k0 + 5]) << 16);
        r3 = bf16rne(src[k0 + 6]) | (bf16rne(src[k0 + 7]) << 16);
    }
    ((uint4*)ws)[(size_t)(kstep * NT2 + nt) * 64 + lane] = make_uint4(r0, r1, r2, r3);
}

// GEMM: 1024 blocks (256 tokgrp x 4 kslice) x 512 threads (8 waves) -> 32 waves/CU.
__global__ __launch_bounds__(512, 4) void moe_gemm(
    const float* __restrict__ x, const float* __restrict__ wfrag,
    float* __restrict__ part) {
    __shared__ __align__(16) char xs[2][XBUF_B];
    __shared__ __align__(16) char wsb[2][WBUF_B];

    const int bid = blockIdx.x;
    const int tg = bid >> 2, ks = bid & 3;
    const int tid = threadIdx.x;
    const int wave = tid >> 6, lane = tid & 63;
    const int l15 = lane & 15, lq = lane >> 4;
    const int T0 = tg * BM;
    const int K0 = ks * KSL;

    const int xtok = wave * 8 + (lane >> 3);
    const float* xsrc = x + (size_t)(T0 + xtok) * DIM + K0
                      + (((lane & 7) ^ (lane >> 3)) << 2);
    const uint4* wg = (const uint4*)wfrag;

    const int mt = wave & 3, nh = wave >> 2;
    const int ctok = mt * 16 + l15;
    const int csw = ctok & 7;

    f32x4 acc[3];
    acc[0] = (f32x4){0.f,0.f,0.f,0.f};
    acc[1] = (f32x4){0.f,0.f,0.f,0.f};
    acc[2] = (f32x4){0.f,0.f,0.f,0.f};

    auto stage = [&](int it) {
        char* xb = xs[it & 1];
        char* wb = wsb[it & 1];
        GLOAD_LDS(xsrc + it * 32, xb + wave * 1024);
        if (wave < NT2) {
            const int kstep = ks * NITER + it;
            GLOAD_LDS(wg + ((size_t)kstep * NT2 + wave) * 64 + lane, wb + wave * 1024);
        }
    };

    stage(0);
    #pragma unroll 1
    for (int it = 0; it < NITER; ++it) {
        __syncthreads();
        if (it + 1 < NITER) stage(it + 1);
        const char* xb = xs[it & 1];
        const char* wb = wsb[it & 1];

        union { unsigned u[4]; bf16x8 v; } af;
        {
            uint4 lo = *(const uint4*)(xb + ctok * 128 + (((lq * 2) ^ csw) << 4));
            uint4 hi = *(const uint4*)(xb + ctok * 128 + (((lq * 2 + 1) ^ csw) << 4));
            af.u[0] = (lo.x >> 16) | (lo.y & 0xFFFF0000u);
            af.u[1] = (lo.z >> 16) | (lo.w & 0xFFFF0000u);
            af.u[2] = (hi.x >> 16) | (hi.y & 0xFFFF0000u);
            af.u[3] = (hi.z >> 16) | (hi.w & 0xFFFF0000u);
        }
        if (nh == 0) {
            bf16x8 b0 = *(const bf16x8*)(wb + 0 * 1024 + lane * 16);
            bf16x8 b1 = *(const bf16x8*)(wb + 1 * 1024 + lane * 16);
            bf16x8 b2 = *(const bf16x8*)(wb + 2 * 1024 + lane * 16);
            acc[0] = __builtin_amdgcn_mfma_f32_16x16x32_bf16(af.v, b0, acc[0], 0, 0, 0);
            acc[1] = __builtin_amdgcn_mfma_f32_16x16x32_bf16(af.v, b1, acc[1], 0, 0, 0);
            acc[2] = __builtin_amdgcn_mfma_f32_16x16x32_bf16(af.v, b2, acc[2], 0, 0, 0);
        } else {
            bf16x8 b0 = *(const bf16x8*)(wb + 3 * 1024 + lane * 16);
            bf16x8 b1 = *(const bf16x8*)(wb + 4 * 1024 + lane * 16);
            acc[0] = __builtin_amdgcn_mfma_f32_16x16x32_bf16(af.v, b0, acc[0], 0, 0, 0);
            acc[1] = __builtin_amdgcn_mfma_f32_16x16x32_bf16(af.v, b1, acc[1], 0, 0, 0);
        }
    }

    float* po = part + (size_t)ks * T_TOKENS * NJP2
              + (size_t)(T0 + mt * 16 + lq * 4) * NJP2 + l15;
    const int ntb = (nh == 0) ? 0 : 3;
    const int ntn = (nh == 0) ? 3 : 2;
    #pragma unroll
    for (int n = 0; n < 3; ++n) {
        if (n < ntn) {
            #pragma unroll
            for (int r = 0; r < 4; ++r)
                po[(size_t)r * NJP2 + (ntb + n) * 16] = acc[n][r];
        }
    }
}

// Epilogue + in-block exact fixup: 512 blocks x 256 threads, 32 tokens/block.
__global__ __launch_bounds__(256, 4) void moe_epi(
    const float* __restrict__ part, const float* __restrict__ x,
    const float* __restrict__ Wg, const float* __restrict__ We,
    float* __restrict__ out, float* __restrict__ sums) {
    __shared__ float slog[32][84];        // 84: 16B-aligned rows
    __shared__ float rp_s[32 * 17];
    __shared__ int   sc_e1[32];
    __shared__ char  flagged[32];
    __shared__ float s_usage[NE], s_rp[NE];
    __shared__ float gl_f[NG], el_f[EPG];
    __shared__ int   s_gi;
    __shared__ float s_gp;

    const int tid = threadIdx.x;
    const int wave = tid >> 6, lane = tid & 63;
    const int T0 = blockIdx.x * 32;
    if (tid < NE) { s_usage[tid] = 0.f; s_rp[tid] = 0.f; }
    if (tid < 32) flagged[tid] = 0;

    // phase 1: float4 gather of 4 partial slabs -> slog
    for (int idx = tid; idx < 32 * 20; idx += 256) {
        const int t = idx / 20, q4 = idx % 20;
        const size_t ro = (size_t)(T0 + t) * NJP2 + q4 * 4;
        float4 v = *(const float4*)(part + ro);
        #pragma unroll
        for (int p = 1; p < KS; ++p) {
            float4 u = *(const float4*)(part + (size_t)p * T_TOKENS * NJP2 + ro);
            v.x += u.x; v.y += u.y; v.z += u.z; v.w += u.w;
        }
        *(float4*)&slog[t][q4 * 4] = v;
    }
    __syncthreads();

    // phase 2: approximate routing + flag marginal tokens
    #pragma unroll
    for (int half = 0; half < 2; ++half) {
        const int t = (tid >> 4) + half * 16;
        const int q = tid & 15;
        const float* o = slog[t];

        float gl0 = o[0], gl1 = o[1], gl2 = o[2], gl3 = o[3];
        float gm = gl0; int gi = 0;
        if (gl1 > gm) { gm = gl1; gi = 1; }
        if (gl2 > gm) { gm = gl2; gi = 2; }
        if (gl3 > gm) { gm = gl3; gi = 3; }
        float g2 = -INFINITY;
        if (gi != 0 && gl0 > g2) g2 = gl0;
        if (gi != 1 && gl1 > g2) g2 = gl1;
        if (gi != 2 && gl2 > g2) g2 = gl2;
        if (gi != 3 && gl3 > g2) g2 = gl3;
        bool flagG = (gm - g2) < TAU;
        float gsum = expf(gl0 - gm) + expf(gl1 - gm) + expf(gl2 - gm) + expf(gl3 - gm);
        float gp = 1.f / gsum;

        float el = o[NG + gi * EPG + q];
        float v1v = el; int i1 = q;
        #pragma unroll
        for (int off = 8; off; off >>= 1) {
            float ov = __shfl_xor(v1v, off, 16);
            int   oi = __shfl_xor(i1, off, 16);
            if (ov > v1v || (ov == v1v && oi < i1)) { v1v = ov; i1 = oi; }
        }
        float v2v = (q == i1) ? -INFINITY : el;
        #pragma unroll
        for (int off = 8; off; off >>= 1)
            v2v = fmaxf(v2v, __shfl_xor(v2v, off, 16));
        bool flagE = (v1v - v2v) < TAU;

        float ep = expf(el - v1v);
        float es = ep;
        #pragma unroll
        for (int off = 8; off; off >>= 1) es += __shfl_xor(es, off, 16);
        float inv = 1.f / es;
        rp_s[t * 17 + q] = gp * ep * inv;

        if (q == 0) {
            sc_e1[t] = gi * EPG + i1;
            if (flagG || flagE) flagged[t] = 1;
        }
    }
    __syncthreads();

    // phase 2.5: exact recompute for flagged tokens (block-wide, sequential)
    for (int t = 0; t < 32; ++t) {
        if (!flagged[t]) continue;
        const float* xrow = x + (size_t)(T0 + t) * DIM;
        float xr[32];
        #pragma unroll
        for (int m = 0; m < 32; ++m) xr[m] = xrow[lane + m * 64];

        auto dotf = [&](const float* w) -> float {
            float s = 0.f;
            #pragma unroll
            for (int m = 0; m < 32; ++m) s = fmaf(xr[m], w[lane + m * 64], s);
            #pragma unroll
            for (int off = 32; off; off >>= 1) s += __shfl_xor(s, off, 64);
            return s;
        };

        {
            float g = dotf(Wg + (size_t)wave * DIM);
            if (lane == 0) gl_f[wave] = g;
        }
        __syncthreads();
        if (tid == 0) {
            float gm = -INFINITY; int gi = 0;
            #pragma unroll
            for (int g = 0; g < NG; ++g)
                if (gl_f[g] > gm) { gm = gl_f[g]; gi = g; }
            float gsum = 0.f;
            #pragma unroll
            for (int g = 0; g < NG; ++g) gsum += expf(gl_f[g] - gm);
            s_gp = 1.f / gsum;
            s_gi = gi;
        }
        __syncthreads();
        const int gi = s_gi;
        #pragma unroll
        for (int j = 0; j < 4; ++j) {
            float e = dotf(We + (size_t)(gi * EPG + wave + j * 4) * DIM);
            if (lane == 0) el_f[wave + j * 4] = e;
        }
        __syncthreads();
        if (tid == 0) {
            float e1 = -INFINITY; int i1 = 0;
            #pragma unroll
            for (int j = 0; j < EPG; ++j)
                if (el_f[j] > e1) { e1 = el_f[j]; i1 = j; }
            float es = 0.f;
            float tmp[EPG];
            #pragma unroll
            for (int j = 0; j < EPG; ++j) {
                float e = expf(el_f[j] - e1);
                tmp[j] = e; es += e;
            }
            float sc = s_gp / es;
            #pragma unroll
            for (int j = 0; j < EPG; ++j) rp_s[t * 17 + j] = tmp[j] * sc;
            sc_e1[t] = gi * EPG + i1;
        }
        __syncthreads();
    }

    // phase 3: float4 scatter of final outputs + LDS expert sums
    float* outD = out;
    float* outC = out + (size_t)T_TOKENS * NE;
    float* outR = out + (size_t)2 * T_TOKENS * NE;
    for (int idx = tid; idx < 32 * 16; idx += 256) {
        const int t = idx >> 4, f4 = idx & 15;
        const int e0 = f4 * 4;
        const int e1i = sc_e1[t];
        const int gi = e1i >> 4;
        float4 dv, rv;
        {
            float d0 = (e0 + 0 == e1i) ? 1.f : 0.f;
            float d1 = (e0 + 1 == e1i) ? 1.f : 0.f;
            float d2 = (e0 + 2 == e1i) ? 1.f : 0.f;
            float d3 = (e0 + 3 == e1i) ? 1.f : 0.f;
            dv = make_float4(d0, d1, d2, d3);
        }
        bool ing = (e0 >> 4) == gi;
        {
            float r0 = ing ? rp_s[t * 17 + ((e0 + 0) & 15)] : 0.f;
            float r1 = ing ? rp_s[t * 17 + ((e0 + 1) & 15)] : 0.f;
            float r2 = ing ? rp_s[t * 17 + ((e0 + 2) & 15)] : 0.f;
            float r3 = ing ? rp_s[t * 17 + ((e0 + 3) & 15)] : 0.f;
            rv = make_float4(r0, r1, r2, r3);
        }
        const size_t ob = (size_t)(T0 + t) * NE + e0;
        *(float4*)&outD[ob] = dv;
        *(float4*)&outC[ob] = dv;
        *(float4*)&outR[ob] = rv;
        if ((e1i >> 2) == (e0 >> 2)) atomicAdd(&s_usage[e1i], 1.f);
        if (ing) {
            atomicAdd(&s_rp[e0 + 0], rv.x);
            atomicAdd(&s_rp[e0 + 1], rv.y);
            atomicAdd(&s_rp[e0 + 2], rv.z);
            atomicAdd(&s_rp[e0 + 3], rv.w);
        }
    }
    __syncthreads();
    if (tid < NE) {
        atomicAdd(&sums[tid], s_usage[tid]);
        atomicAdd(&sums[NE + tid], s_rp[tid]);
    }
}

__global__ void moe_finalize(const float* __restrict__ sums, float* __restrict__ out) {
    int l = threadIdx.x;
    float v = sums[l] * sums[NE + l];
    #pragma unroll
    for (int off = 32; off; off >>= 1) v += __shfl_down(v, off, 64);
    if (l == 0) {
        float N = (float)T_TOKENS;
        out[(size_t)3 * T_TOKENS * NE] = v * (float)NE / (N * N);
    }
}

extern "C" void kernel_launch(void* const* d_in, const int* in_sizes, int n_in,
                              void* d_out, int out_size, void* d_ws, size_t ws_size,
                              hipStream_t stream) {
    const float* x  = (const float*)d_in[0];
    const float* Wg = (const float*)d_in[1];
    const float* We = (const float*)d_in[2];
    float* out = (float*)d_out;
    float* ws  = (float*)d_ws;

    float* wfrag = ws;
    float* part  = ws + P_OFF;
    float* sums  = ws + SUM_OFF;

    moe_prep<<<64 * NT2, 64, 0, stream>>>(Wg, We, wfrag, sums);
    moe_gemm<<<(T_TOKENS / BM) * KS, 512, 0, stream>>>(x, wfrag, part);
    moe_epi<<<T_TOKENS / 32, 256, 0, stream>>>(part, x, Wg, We, out, sums);
    moe_finalize<<<1, 64, 0, stream>>>(sums, out);
}

// Round 19
// 82.856 us; speedup vs baseline: 1.2202x; 1.2202x over previous
//
#include <hip/hip_runtime.h>
#include <cmath>

#define T_TOKENS 16384
#define DIM 2048
#define NG 4
#define EPG 16
#define NE 64
#define NJ2 68          // 4 group + 64 expert rows (complexity MLP dead: k==1 always)
#define NT2 5           // n-tiles of 16 (80 padded)
#define NJP2 80
#define BM 64           // tokens per gemm block
#define KS 4            // K-split
#define KSL (DIM / KS)  // 512
#define NITER (KSL / 32)  // 16
#define TAU 0.02f

#define XBUF_B 8192     // 64 tok * 32 f * 4B per iter
#define WBUF_B 5120     // 5 cells * 1KB

typedef __attribute__((ext_vector_type(8))) short bf16x8;
typedef __attribute__((ext_vector_type(4))) float f32x4;

// ws float-offsets
#define WF_FLOATS (64 * NT2 * 64 * 4)             // 81920 floats
#define P_OFF WF_FLOATS
#define P_FLOATS ((size_t)KS * T_TOKENS * NJP2)   // 5.24M floats (21 MB)
#define SUM_OFF (P_OFF + P_FLOATS)
#define CNT_OFF (SUM_OFF + 128)
#define LIST_OFF (CNT_OFF + 4)

static __device__ inline unsigned bf16rne(float x) {
    unsigned u = __float_as_uint(x);
    return (u + 0x7FFFu + ((u >> 16) & 1u)) >> 16;
}

#define GLOAD_LDS(gsrc, ldst) \
    __builtin_amdgcn_global_load_lds( \
        (const __attribute__((address_space(1))) void*)(gsrc), \
        (__attribute__((address_space(3))) void*)(ldst), 16, 0, 0)

// Fragment-linear bf16 weights: [kstep 64][tile 5][lane 64][16B].
__global__ void moe_prep(const float* __restrict__ Wg, const float* __restrict__ We,
                         float* __restrict__ ws, float* __restrict__ sums,
                         int* __restrict__ cnt) {
    int bid = blockIdx.x;                 // 320
    int kstep = bid / NT2, nt = bid % NT2;
    int lane = threadIdx.x;
    if (bid == 0) {
        sums[lane] = 0.f; sums[64 + lane] = 0.f;
        if (lane == 0) *cnt = 0;
    }
    int row = nt * 16 + (lane & 15);
    int k0 = kstep * 32 + (lane >> 4) * 8;
    const float* src = nullptr;
    if (row < NG)        src = Wg + (size_t)row * DIM;
    else if (row < NJ2)  src = We + (size_t)(row - NG) * DIM;
    unsigned r0 = 0, r1 = 0, r2 = 0, r3 = 0;
    if (src) {
        r0 = bf16rne(src[k0 + 0]) | (bf16rne(src[k0 + 1]) << 16);
        r1 = bf16rne(src[k0 + 2]) | (bf16rne(src[k0 + 3]) << 16);
        r2 = bf16rne(src[k0 + 4]) | (bf16rne(src[k0 + 5]) << 16);
        r3 = bf16rne(src[k0 + 6]) | (bf16rne(src[k0 + 7]) << 16);
    }
    ((uint4*)ws)[(size_t)(kstep * NT2 + nt) * 64 + lane] = make_uint4(r0, r1, r2, r3);
}

// GEMM: 1024 blocks (256 tokgrp x 4 kslice) x 512 threads (8 waves) -> 32 waves/CU.
__global__ __launch_bounds__(512, 4) void moe_gemm(
    const float* __restrict__ x, const float* __restrict__ wfrag,
    float* __restrict__ part) {
    __shared__ __align__(16) char xs[2][XBUF_B];
    __shared__ __align__(16) char wsb[2][WBUF_B];

    const int bid = blockIdx.x;
    const int tg = bid >> 2, ks = bid & 3;
    const int tid = threadIdx.x;
    const int wave = tid >> 6, lane = tid & 63;
    const int l15 = lane & 15, lq = lane >> 4;
    const int T0 = tg * BM;
    const int K0 = ks * KSL;

    const int xtok = wave * 8 + (lane >> 3);
    const float* xsrc = x + (size_t)(T0 + xtok) * DIM + K0
                      + (((lane & 7) ^ (lane >> 3)) << 2);
    const uint4* wg = (const uint4*)wfrag;

    const int mt = wave & 3, nh = wave >> 2;
    const int ctok = mt * 16 + l15;
    const int csw = ctok & 7;

    f32x4 acc[3];
    acc[0] = (f32x4){0.f,0.f,0.f,0.f};
    acc[1] = (f32x4){0.f,0.f,0.f,0.f};
    acc[2] = (f32x4){0.f,0.f,0.f,0.f};

    auto stage = [&](int it) {
        char* xb = xs[it & 1];
        char* wb = wsb[it & 1];
        GLOAD_LDS(xsrc + it * 32, xb + wave * 1024);
        if (wave < NT2) {
            const int kstep = ks * NITER + it;
            GLOAD_LDS(wg + ((size_t)kstep * NT2 + wave) * 64 + lane, wb + wave * 1024);
        }
    };

    stage(0);
    #pragma unroll 1
    for (int it = 0; it < NITER; ++it) {
        __syncthreads();
        if (it + 1 < NITER) stage(it + 1);
        const char* xb = xs[it & 1];
        const char* wb = wsb[it & 1];

        union { unsigned u[4]; bf16x8 v; } af;
        {
            uint4 lo = *(const uint4*)(xb + ctok * 128 + (((lq * 2) ^ csw) << 4));
            uint4 hi = *(const uint4*)(xb + ctok * 128 + (((lq * 2 + 1) ^ csw) << 4));
            af.u[0] = (lo.x >> 16) | (lo.y & 0xFFFF0000u);
            af.u[1] = (lo.z >> 16) | (lo.w & 0xFFFF0000u);
            af.u[2] = (hi.x >> 16) | (hi.y & 0xFFFF0000u);
            af.u[3] = (hi.z >> 16) | (hi.w & 0xFFFF0000u);
        }
        if (nh == 0) {
            bf16x8 b0 = *(const bf16x8*)(wb + 0 * 1024 + lane * 16);
            bf16x8 b1 = *(const bf16x8*)(wb + 1 * 1024 + lane * 16);
            bf16x8 b2 = *(const bf16x8*)(wb + 2 * 1024 + lane * 16);
            acc[0] = __builtin_amdgcn_mfma_f32_16x16x32_bf16(af.v, b0, acc[0], 0, 0, 0);
            acc[1] = __builtin_amdgcn_mfma_f32_16x16x32_bf16(af.v, b1, acc[1], 0, 0, 0);
            acc[2] = __builtin_amdgcn_mfma_f32_16x16x32_bf16(af.v, b2, acc[2], 0, 0, 0);
        } else {
            bf16x8 b0 = *(const bf16x8*)(wb + 3 * 1024 + lane * 16);
            bf16x8 b1 = *(const bf16x8*)(wb + 4 * 1024 + lane * 16);
            acc[0] = __builtin_amdgcn_mfma_f32_16x16x32_bf16(af.v, b0, acc[0], 0, 0, 0);
            acc[1] = __builtin_amdgcn_mfma_f32_16x16x32_bf16(af.v, b1, acc[1], 0, 0, 0);
        }
    }

    float* po = part + (size_t)ks * T_TOKENS * NJP2
              + (size_t)(T0 + mt * 16 + lq * 4) * NJP2 + l15;
    const int ntb = (nh == 0) ? 0 : 3;
    const int ntn = (nh == 0) ? 3 : 2;
    #pragma unroll
    for (int n = 0; n < 3; ++n) {
        if (n < ntn) {
            #pragma unroll
            for (int r = 0; r < 4; ++r)
                po[(size_t)r * NJP2 + (ntb + n) * 16] = acc[n][r];
        }
    }
}

// Epilogue: 1024 blocks x 256 threads, 16 tokens/block, float4 gather + float4 scatter.
__global__ __launch_bounds__(256, 4) void moe_epi(
    const float* __restrict__ part, float* __restrict__ out,
    float* __restrict__ sums, int* __restrict__ cnt, int4* __restrict__ list) {
    __shared__ float slog[16][84];        // 84: 16B-aligned rows
    __shared__ float rp_s[16 * 17];
    __shared__ int   sc_e1[16];
    __shared__ float s_usage[NE], s_rp[NE];

    const int tid = threadIdx.x;
    const int T0 = blockIdx.x * 16;
    if (tid < NE) { s_usage[tid] = 0.f; s_rp[tid] = 0.f; }

    // phase 1: float4 gather of 4 partial slabs -> slog
    for (int idx = tid; idx < 16 * 20; idx += 256) {
        const int t = idx / 20, q4 = idx % 20;
        const size_t ro = (size_t)(T0 + t) * NJP2 + q4 * 4;
        float4 v = *(const float4*)(part + ro);
        #pragma unroll
        for (int p = 1; p < KS; ++p) {
            float4 u = *(const float4*)(part + (size_t)p * T_TOKENS * NJP2 + ro);
            v.x += u.x; v.y += u.y; v.z += u.z; v.w += u.w;
        }
        *(float4*)&slog[t][q4 * 4] = v;
    }
    __syncthreads();

    // phase 2: 16-lane group per token (16 tokens, 256 threads)
    {
        const int t = tid >> 4;
        const int q = tid & 15;
        const int tok = T0 + t;
        const float* o = slog[t];

        float gl0 = o[0], gl1 = o[1], gl2 = o[2], gl3 = o[3];
        float gm = gl0; int gi = 0;
        if (gl1 > gm) { gm = gl1; gi = 1; }
        if (gl2 > gm) { gm = gl2; gi = 2; }
        if (gl3 > gm) { gm = gl3; gi = 3; }
        float g2 = -INFINITY;
        if (gi != 0 && gl0 > g2) g2 = gl0;
        if (gi != 1 && gl1 > g2) g2 = gl1;
        if (gi != 2 && gl2 > g2) g2 = gl2;
        if (gi != 3 && gl3 > g2) g2 = gl3;
        bool flagG = (gm - g2) < TAU;
        float gsum = expf(gl0 - gm) + expf(gl1 - gm) + expf(gl2 - gm) + expf(gl3 - gm);
        float gp = 1.f / gsum;

        float el = o[NG + gi * EPG + q];
        float v1v = el; int i1 = q;
        #pragma unroll
        for (int off = 8; off; off >>= 1) {
            float ov = __shfl_xor(v1v, off, 16);
            int   oi = __shfl_xor(i1, off, 16);
            if (ov > v1v || (ov == v1v && oi < i1)) { v1v = ov; i1 = oi; }
        }
        float v2v = (q == i1) ? -INFINITY : el;
        #pragma unroll
        for (int off = 8; off; off >>= 1)
            v2v = fmaxf(v2v, __shfl_xor(v2v, off, 16));
        bool flagE = (v1v - v2v) < TAU;

        float ep = expf(el - v1v);
        float es = ep;
        #pragma unroll
        for (int off = 8; off; off >>= 1) es += __shfl_xor(es, off, 16);
        float inv = 1.f / es;
        rp_s[t * 17 + q] = gp * ep * inv;

        if (q == 0) {
            sc_e1[t] = gi * EPG + i1;
            if (flagG || flagE) {
                int p = atomicAdd(cnt, 1);
                list[p] = make_int4(tok, 0, 0, 0);
            }
        }
    }
    __syncthreads();

    // phase 3: float4 scatter + LDS expert sums
    float* outD = out;
    float* outC = out + (size_t)T_TOKENS * NE;
    float* outR = out + (size_t)2 * T_TOKENS * NE;
    {
        const int t = tid >> 4, f4 = tid & 15;
        const int e0 = f4 * 4;
        const int e1i = sc_e1[t];
        const int gi = e1i >> 4;
        float4 dv, rv;
        {
            float d0 = (e0 + 0 == e1i) ? 1.f : 0.f;
            float d1 = (e0 + 1 == e1i) ? 1.f : 0.f;
            float d2 = (e0 + 2 == e1i) ? 1.f : 0.f;
            float d3 = (e0 + 3 == e1i) ? 1.f : 0.f;
            dv = make_float4(d0, d1, d2, d3);
        }
        bool ing = (e0 >> 4) == gi;
        {
            float r0 = ing ? rp_s[t * 17 + ((e0 + 0) & 15)] : 0.f;
            float r1 = ing ? rp_s[t * 17 + ((e0 + 1) & 15)] : 0.f;
            float r2 = ing ? rp_s[t * 17 + ((e0 + 2) & 15)] : 0.f;
            float r3 = ing ? rp_s[t * 17 + ((e0 + 3) & 15)] : 0.f;
            rv = make_float4(r0, r1, r2, r3);
        }
        const size_t ob = (size_t)(T0 + t) * NE + e0;
        *(float4*)&outD[ob] = dv;
        *(float4*)&outC[ob] = dv;
        *(float4*)&outR[ob] = rv;
        if ((e1i >> 2) == (e0 >> 2)) atomicAdd(&s_usage[e1i], 1.f);
        if (ing) {
            atomicAdd(&s_rp[e0 + 0], rv.x);
            atomicAdd(&s_rp[e0 + 1], rv.y);
            atomicAdd(&s_rp[e0 + 2], rv.z);
            atomicAdd(&s_rp[e0 + 3], rv.w);
        }
    }
    __syncthreads();
    if (tid < NE) {
        atomicAdd(&sums[tid], s_usage[tid]);
        atomicAdd(&sums[NE + tid], s_rp[tid]);
    }
}

// exact fixup: one block (4 waves) per flagged token
__global__ __launch_bounds__(256, 4) void moe_fix(
    const float* __restrict__ x, const float* __restrict__ Wg,
    const float* __restrict__ We, float* __restrict__ out,
    float* __restrict__ sums, const int* __restrict__ cnt,
    const int4* __restrict__ list) {
    __shared__ float gl_s[NG];
    __shared__ float el_s[EPG];
    __shared__ float rp_row[EPG];
    __shared__ int   s_gi, s_e1;
    __shared__ float s_gp;

    const int tid = threadIdx.x;
    const int wave = tid >> 6, lane = tid & 63;
    const int n = *cnt;

    for (int i = blockIdx.x; i < n; i += gridDim.x) {
        const int tok = list[i].x;
        const float* xrow = x + (size_t)tok * DIM;
        float xr[32];
        #pragma unroll
        for (int m = 0; m < 32; ++m) xr[m] = xrow[lane + m * 64];

        auto dotf = [&](const float* w) -> float {
            float s = 0.f;
            #pragma unroll
            for (int m = 0; m < 32; ++m) s = fmaf(xr[m], w[lane + m * 64], s);
            #pragma unroll
            for (int off = 32; off; off >>= 1) s += __shfl_xor(s, off, 64);
            return s;
        };

        {
            float g = dotf(Wg + (size_t)wave * DIM);
            if (lane == 0) gl_s[wave] = g;
        }
        __syncthreads();

        if (tid == 0) {
            float gm = -INFINITY; int gi = 0;
            #pragma unroll
            for (int g = 0; g < NG; ++g)
                if (gl_s[g] > gm) { gm = gl_s[g]; gi = g; }
            float gsum = 0.f;
            #pragma unroll
            for (int g = 0; g < NG; ++g) gsum += expf(gl_s[g] - gm);
            s_gp = 1.f / gsum;
            s_gi = gi;
        }
        __syncthreads();

        const int gi = s_gi;
        for (int j = wave; j < EPG; j += 4) {
            float e = dotf(We + (size_t)(gi * EPG + j) * DIM);
            if (lane == 0) el_s[j] = e;
        }
        __syncthreads();

        if (tid == 0) {
            float e1 = -INFINITY; int i1 = 0;
            #pragma unroll
            for (int j = 0; j < EPG; ++j)
                if (el_s[j] > e1) { e1 = el_s[j]; i1 = j; }
            float es = 0.f;
            #pragma unroll
            for (int j = 0; j < EPG; ++j) {
                float e = expf(el_s[j] - e1);
                rp_row[j] = e;
                es += e;
            }
            float sc = s_gp / es;
            #pragma unroll
            for (int j = 0; j < EPG; ++j) rp_row[j] *= sc;
            s_e1 = gi * EPG + i1;
        }
        __syncthreads();

        if (tid < NE) {
            const int e = tid;
            float newD = (e == s_e1) ? 1.f : 0.f;
            float newR = ((e >> 4) == gi) ? rp_row[e & 15] : 0.f;
            size_t ob = (size_t)tok * NE + e;
            float oldD = out[ob];
            float oldR = out[(size_t)2 * T_TOKENS * NE + ob];
            out[ob] = newD;
            out[(size_t)T_TOKENS * NE + ob] = newD;
            out[(size_t)2 * T_TOKENS * NE + ob] = newR;
            float dD = newD - oldD, dR = newR - oldR;
            if (dD != 0.f) atomicAdd(&sums[e], dD);
            if (dR != 0.f) atomicAdd(&sums[NE + e], dR);
        }
        __syncthreads();
    }
}

__global__ void moe_finalize(const float* __restrict__ sums, float* __restrict__ out) {
    int l = threadIdx.x;
    float v = sums[l] * sums[NE + l];
    #pragma unroll
    for (int off = 32; off; off >>= 1) v += __shfl_down(v, off, 64);
    if (l == 0) {
        float N = (float)T_TOKENS;
        out[(size_t)3 * T_TOKENS * NE] = v * (float)NE / (N * N);
    }
}

extern "C" void kernel_launch(void* const* d_in, const int* in_sizes, int n_in,
                              void* d_out, int out_size, void* d_ws, size_t ws_size,
                              hipStream_t stream) {
    const float* x  = (const float*)d_in[0];
    const float* Wg = (const float*)d_in[1];
    const float* We = (const float*)d_in[2];
    float* out = (float*)d_out;
    float* ws  = (float*)d_ws;

    float* wfrag = ws;
    float* part  = ws + P_OFF;
    float* sums  = ws + SUM_OFF;
    int*   cnt   = (int*)(ws + CNT_OFF);
    int4*  list  = (int4*)(ws + LIST_OFF);

    moe_prep<<<64 * NT2, 64, 0, stream>>>(Wg, We, wfrag, sums, cnt);
    moe_gemm<<<(T_TOKENS / BM) * KS, 512, 0, stream>>>(x, wfrag, part);
    moe_epi<<<T_TOKENS / 16, 256, 0, stream>>>(part, out, sums, cnt, list);
    moe_fix<<<1024, 256, 0, stream>>>(x, Wg, We, out, sums, cnt, list);
    moe_finalize<<<1, 64, 0, stream>>>(sums, out);
}

// Round 20
// 74.686 us; speedup vs baseline: 1.3537x; 1.1094x over previous
//
#include <hip/hip_runtime.h>
#include <cmath>

#define T_TOKENS 16384
#define DIM 2048
#define NG 4
#define EPG 16
#define NE 64
#define NJ2 68          // 4 group + 64 expert rows (complexity MLP dead: k==1 always)
#define NT2 5           // n-tiles of 16 (80 padded)
#define NJP2 80
#define BM 64           // tokens per gemm block
#define KS 4            // K-split
#define KSL (DIM / KS)  // 512
#define NITER (KSL / 32)  // 16
#define TAU 0.02f

#define XBUF_B 8192     // 64 tok * 32 f * 4B per iter
#define WBUF_B 5120     // 5 cells * 1KB

typedef __attribute__((ext_vector_type(8))) short bf16x8;
typedef __attribute__((ext_vector_type(4))) float f32x4;

// ws float-offsets
#define WF_FLOATS (64 * NT2 * 64 * 4)             // 81920 floats
#define P_OFF WF_FLOATS
#define P_FLOATS ((size_t)KS * T_TOKENS * NJP2)   // 5.24M floats (21 MB)
#define SUM_OFF (P_OFF + P_FLOATS)
#define CNT_OFF (SUM_OFF + 128)
#define LIST_OFF (CNT_OFF + 4)

static __device__ inline unsigned bf16rne(float x) {
    unsigned u = __float_as_uint(x);
    return (u + 0x7FFFu + ((u >> 16) & 1u)) >> 16;
}

#define GLOAD_LDS(gsrc, ldst) \
    __builtin_amdgcn_global_load_lds( \
        (const __attribute__((address_space(1))) void*)(gsrc), \
        (__attribute__((address_space(3))) void*)(ldst), 16, 0, 0)

// Fragment-linear bf16 weights: [kstep 64][tile 5][lane 64][16B].
__global__ void moe_prep(const float* __restrict__ Wg, const float* __restrict__ We,
                         float* __restrict__ ws, float* __restrict__ sums,
                         int* __restrict__ cnt) {
    int bid = blockIdx.x;                 // 320
    int kstep = bid / NT2, nt = bid % NT2;
    int lane = threadIdx.x;
    if (bid == 0) {
        sums[lane] = 0.f; sums[64 + lane] = 0.f;
        if (lane == 0) *cnt = 0;
    }
    int row = nt * 16 + (lane & 15);
    int k0 = kstep * 32 + (lane >> 4) * 8;
    const float* src = nullptr;
    if (row < NG)        src = Wg + (size_t)row * DIM;
    else if (row < NJ2)  src = We + (size_t)(row - NG) * DIM;
    unsigned r0 = 0, r1 = 0, r2 = 0, r3 = 0;
    if (src) {
        r0 = bf16rne(src[k0 + 0]) | (bf16rne(src[k0 + 1]) << 16);
        r1 = bf16rne(src[k0 + 2]) | (bf16rne(src[k0 + 3]) << 16);
        r2 = bf16rne(src[k0 + 4]) | (bf16rne(src[k0 + 5]) << 16);
        r3 = bf16rne(src[k0 + 6]) | (bf16rne(src[k0 + 7]) << 16);
    }
    ((uint4*)ws)[(size_t)(kstep * NT2 + nt) * 64 + lane] = make_uint4(r0, r1, r2, r3);
}

// GEMM: 1024 blocks (256 tokgrp x 4 kslice) x 512 threads (8 waves) -> 32 waves/CU.
__global__ __launch_bounds__(512, 4) void moe_gemm(
    const float* __restrict__ x, const float* __restrict__ wfrag,
    float* __restrict__ part) {
    __shared__ __align__(16) char xs[2][XBUF_B];
    __shared__ __align__(16) char wsb[2][WBUF_B];

    const int bid = blockIdx.x;
    const int tg = bid >> 2, ks = bid & 3;
    const int tid = threadIdx.x;
    const int wave = tid >> 6, lane = tid & 63;
    const int l15 = lane & 15, lq = lane >> 4;
    const int T0 = tg * BM;
    const int K0 = ks * KSL;

    const int xtok = wave * 8 + (lane >> 3);
    const float* xsrc = x + (size_t)(T0 + xtok) * DIM + K0
                      + (((lane & 7) ^ (lane >> 3)) << 2);
    const uint4* wg = (const uint4*)wfrag;

    const int mt = wave & 3, nh = wave >> 2;
    const int ctok = mt * 16 + l15;
    const int csw = ctok & 7;

    f32x4 acc[3];
    acc[0] = (f32x4){0.f,0.f,0.f,0.f};
    acc[1] = (f32x4){0.f,0.f,0.f,0.f};
    acc[2] = (f32x4){0.f,0.f,0.f,0.f};

    auto stage = [&](int it) {
        char* xb = xs[it & 1];
        char* wb = wsb[it & 1];
        GLOAD_LDS(xsrc + it * 32, xb + wave * 1024);
        if (wave < NT2) {
            const int kstep = ks * NITER + it;
            GLOAD_LDS(wg + ((size_t)kstep * NT2 + wave) * 64 + lane, wb + wave * 1024);
        }
    };

    stage(0);
    #pragma unroll 1
    for (int it = 0; it < NITER; ++it) {
        __syncthreads();
        if (it + 1 < NITER) stage(it + 1);
        const char* xb = xs[it & 1];
        const char* wb = wsb[it & 1];

        union { unsigned u[4]; bf16x8 v; } af;
        {
            uint4 lo = *(const uint4*)(xb + ctok * 128 + (((lq * 2) ^ csw) << 4));
            uint4 hi = *(const uint4*)(xb + ctok * 128 + (((lq * 2 + 1) ^ csw) << 4));
            af.u[0] = (lo.x >> 16) | (lo.y & 0xFFFF0000u);
            af.u[1] = (lo.z >> 16) | (lo.w & 0xFFFF0000u);
            af.u[2] = (hi.x >> 16) | (hi.y & 0xFFFF0000u);
            af.u[3] = (hi.z >> 16) | (hi.w & 0xFFFF0000u);
        }
        if (nh == 0) {
            bf16x8 b0 = *(const bf16x8*)(wb + 0 * 1024 + lane * 16);
            bf16x8 b1 = *(const bf16x8*)(wb + 1 * 1024 + lane * 16);
            bf16x8 b2 = *(const bf16x8*)(wb + 2 * 1024 + lane * 16);
            acc[0] = __builtin_amdgcn_mfma_f32_16x16x32_bf16(af.v, b0, acc[0], 0, 0, 0);
            acc[1] = __builtin_amdgcn_mfma_f32_16x16x32_bf16(af.v, b1, acc[1], 0, 0, 0);
            acc[2] = __builtin_amdgcn_mfma_f32_16x16x32_bf16(af.v, b2, acc[2], 0, 0, 0);
        } else {
            bf16x8 b0 = *(const bf16x8*)(wb + 3 * 1024 + lane * 16);
            bf16x8 b1 = *(const bf16x8*)(wb + 4 * 1024 + lane * 16);
            acc[0] = __builtin_amdgcn_mfma_f32_16x16x32_bf16(af.v, b0, acc[0], 0, 0, 0);
            acc[1] = __builtin_amdgcn_mfma_f32_16x16x32_bf16(af.v, b1, acc[1], 0, 0, 0);
        }
    }

    float* po = part + (size_t)ks * T_TOKENS * NJP2
              + (size_t)(T0 + mt * 16 + lq * 4) * NJP2 + l15;
    const int ntb = (nh == 0) ? 0 : 3;
    const int ntn = (nh == 0) ? 3 : 2;
    #pragma unroll
    for (int n = 0; n < 3; ++n) {
        if (n < ntn) {
            #pragma unroll
            for (int r = 0; r < 4; ++r)
                po[(size_t)r * NJP2 + (ntb + n) * 16] = acc[n][r];
        }
    }
}

// Epilogue: 512 blocks x 256 threads, 32 tokens/block, float4 gather + float4 scatter.
__global__ __launch_bounds__(256, 4) void moe_epi(
    const float* __restrict__ part, float* __restrict__ out,
    float* __restrict__ sums, int* __restrict__ cnt, int4* __restrict__ list) {
    __shared__ float slog[32][84];        // 84: 16B-aligned rows
    __shared__ float rp_s[32 * 17];
    __shared__ int   sc_e1[32];
    __shared__ float s_usage[NE], s_rp[NE];

    const int tid = threadIdx.x;
    const int T0 = blockIdx.x * 32;
    if (tid < NE) { s_usage[tid] = 0.f; s_rp[tid] = 0.f; }

    // phase 1: float4 gather of 4 partial slabs -> slog
    for (int idx = tid; idx < 32 * 20; idx += 256) {
        const int t = idx / 20, q4 = idx % 20;
        const size_t ro = (size_t)(T0 + t) * NJP2 + q4 * 4;
        float4 v = *(const float4*)(part + ro);
        #pragma unroll
        for (int p = 1; p < KS; ++p) {
            float4 u = *(const float4*)(part + (size_t)p * T_TOKENS * NJP2 + ro);
            v.x += u.x; v.y += u.y; v.z += u.z; v.w += u.w;
        }
        *(float4*)&slog[t][q4 * 4] = v;
    }
    __syncthreads();

    // phase 2: 16-lane group per token, 2 halves of 16 tokens
    #pragma unroll
    for (int half = 0; half < 2; ++half) {
        const int t = (tid >> 4) + half * 16;
        const int q = tid & 15;
        const int tok = T0 + t;
        const float* o = slog[t];

        float gl0 = o[0], gl1 = o[1], gl2 = o[2], gl3 = o[3];
        float gm = gl0; int gi = 0;
        if (gl1 > gm) { gm = gl1; gi = 1; }
        if (gl2 > gm) { gm = gl2; gi = 2; }
        if (gl3 > gm) { gm = gl3; gi = 3; }
        float g2 = -INFINITY;
        if (gi != 0 && gl0 > g2) g2 = gl0;
        if (gi != 1 && gl1 > g2) g2 = gl1;
        if (gi != 2 && gl2 > g2) g2 = gl2;
        if (gi != 3 && gl3 > g2) g2 = gl3;
        bool flagG = (gm - g2) < TAU;
        float gsum = expf(gl0 - gm) + expf(gl1 - gm) + expf(gl2 - gm) + expf(gl3 - gm);
        float gp = 1.f / gsum;

        float el = o[NG + gi * EPG + q];
        float v1v = el; int i1 = q;
        #pragma unroll
        for (int off = 8; off; off >>= 1) {
            float ov = __shfl_xor(v1v, off, 16);
            int   oi = __shfl_xor(i1, off, 16);
            if (ov > v1v || (ov == v1v && oi < i1)) { v1v = ov; i1 = oi; }
        }
        float v2v = (q == i1) ? -INFINITY : el;
        #pragma unroll
        for (int off = 8; off; off >>= 1)
            v2v = fmaxf(v2v, __shfl_xor(v2v, off, 16));
        bool flagE = (v1v - v2v) < TAU;

        float ep = expf(el - v1v);
        float es = ep;
        #pragma unroll
        for (int off = 8; off; off >>= 1) es += __shfl_xor(es, off, 16);
        float inv = 1.f / es;
        rp_s[t * 17 + q] = gp * ep * inv;

        if (q == 0) {
            sc_e1[t] = gi * EPG + i1;
            if (flagG || flagE) {
                int p = atomicAdd(cnt, 1);
                list[p] = make_int4(tok, 0, 0, 0);
            }
        }
    }
    __syncthreads();

    // phase 3: float4 scatter of dispatch/combine/router_probs + LDS expert sums
    float* outD = out;
    float* outC = out + (size_t)T_TOKENS * NE;
    float* outR = out + (size_t)2 * T_TOKENS * NE;
    for (int idx = tid; idx < 32 * 16; idx += 256) {
        const int t = idx >> 4, f4 = idx & 15;
        const int e0 = f4 * 4;
        const int e1i = sc_e1[t];
        const int gi = e1i >> 4;
        float4 dv, rv;
        {
            float d0 = (e0 + 0 == e1i) ? 1.f : 0.f;
            float d1 = (e0 + 1 == e1i) ? 1.f : 0.f;
            float d2 = (e0 + 2 == e1i) ? 1.f : 0.f;
            float d3 = (e0 + 3 == e1i) ? 1.f : 0.f;
            dv = make_float4(d0, d1, d2, d3);
        }
        bool ing = (e0 >> 4) == gi;
        {
            float r0 = ing ? rp_s[t * 17 + ((e0 + 0) & 15)] : 0.f;
            float r1 = ing ? rp_s[t * 17 + ((e0 + 1) & 15)] : 0.f;
            float r2 = ing ? rp_s[t * 17 + ((e0 + 2) & 15)] : 0.f;
            float r3 = ing ? rp_s[t * 17 + ((e0 + 3) & 15)] : 0.f;
            rv = make_float4(r0, r1, r2, r3);
        }
        const size_t ob = (size_t)(T0 + t) * NE + e0;
        *(float4*)&outD[ob] = dv;
        *(float4*)&outC[ob] = dv;
        *(float4*)&outR[ob] = rv;
        if ((e1i >> 2) == (e0 >> 2)) atomicAdd(&s_usage[e1i], 1.f);
        if (ing) {
            atomicAdd(&s_rp[e0 + 0], rv.x);
            atomicAdd(&s_rp[e0 + 1], rv.y);
            atomicAdd(&s_rp[e0 + 2], rv.z);
            atomicAdd(&s_rp[e0 + 3], rv.w);
        }
    }
    __syncthreads();
    if (tid < NE) {
        atomicAdd(&sums[tid], s_usage[tid]);
        atomicAdd(&sums[NE + tid], s_rp[tid]);
    }
}

// exact fixup: one block (4 waves) per flagged token
__global__ __launch_bounds__(256, 4) void moe_fix(
    const float* __restrict__ x, const float* __restrict__ Wg,
    const float* __restrict__ We, float* __restrict__ out,
    float* __restrict__ sums, const int* __restrict__ cnt,
    const int4* __restrict__ list) {
    __shared__ float gl_s[NG];
    __shared__ float el_s[EPG];
    __shared__ float rp_row[EPG];
    __shared__ int   s_gi, s_e1;
    __shared__ float s_gp;

    const int tid = threadIdx.x;
    const int wave = tid >> 6, lane = tid & 63;
    const int n = *cnt;

    for (int i = blockIdx.x; i < n; i += gridDim.x) {
        const int tok = list[i].x;
        const float* xrow = x + (size_t)tok * DIM;
        float xr[32];
        #pragma unroll
        for (int m = 0; m < 32; ++m) xr[m] = xrow[lane + m * 64];

        auto dotf = [&](const float* w) -> float {
            float s = 0.f;
            #pragma unroll
            for (int m = 0; m < 32; ++m) s = fmaf(xr[m], w[lane + m * 64], s);
            #pragma unroll
            for (int off = 32; off; off >>= 1) s += __shfl_xor(s, off, 64);
            return s;
        };

        {
            float g = dotf(Wg + (size_t)wave * DIM);
            if (lane == 0) gl_s[wave] = g;
        }
        __syncthreads();

        if (tid == 0) {
            float gm = -INFINITY; int gi = 0;
            #pragma unroll
            for (int g = 0; g < NG; ++g)
                if (gl_s[g] > gm) { gm = gl_s[g]; gi = g; }
            float gsum = 0.f;
            #pragma unroll
            for (int g = 0; g < NG; ++g) gsum += expf(gl_s[g] - gm);
            s_gp = 1.f / gsum;
            s_gi = gi;
        }
        __syncthreads();

        const int gi = s_gi;
        for (int j = wave; j < EPG; j += 4) {
            float e = dotf(We + (size_t)(gi * EPG + j) * DIM);
            if (lane == 0) el_s[j] = e;
        }
        __syncthreads();

        if (tid == 0) {
            float e1 = -INFINITY; int i1 = 0;
            #pragma unroll
            for (int j = 0; j < EPG; ++j)
                if (el_s[j] > e1) { e1 = el_s[j]; i1 = j; }
            float es = 0.f;
            #pragma unroll
            for (int j = 0; j < EPG; ++j) {
                float e = expf(el_s[j] - e1);
                rp_row[j] = e;
                es += e;
            }
            float sc = s_gp / es;
            #pragma unroll
            for (int j = 0; j < EPG; ++j) rp_row[j] *= sc;
            s_e1 = gi * EPG + i1;
        }
        __syncthreads();

        if (tid < NE) {
            const int e = tid;
            float newD = (e == s_e1) ? 1.f : 0.f;
            float newR = ((e >> 4) == gi) ? rp_row[e & 15] : 0.f;
            size_t ob = (size_t)tok * NE + e;
            float oldD = out[ob];
            float oldR = out[(size_t)2 * T_TOKENS * NE + ob];
            out[ob] = newD;
            out[(size_t)T_TOKENS * NE + ob] = newD;
            out[(size_t)2 * T_TOKENS * NE + ob] = newR;
            float dD = newD - oldD, dR = newR - oldR;
            if (dD != 0.f) atomicAdd(&sums[e], dD);
            if (dR != 0.f) atomicAdd(&sums[NE + e], dR);
        }
        __syncthreads();
    }
}

__global__ void moe_finalize(const float* __restrict__ sums, float* __restrict__ out) {
    int l = threadIdx.x;
    float v = sums[l] * sums[NE + l];
    #pragma unroll
    for (int off = 32; off; off >>= 1) v += __shfl_down(v, off, 64);
    if (l == 0) {
        float N = (float)T_TOKENS;
        out[(size_t)3 * T_TOKENS * NE] = v * (float)NE / (N * N);
    }
}

extern "C" void kernel_launch(void* const* d_in, const int* in_sizes, int n_in,
                              void* d_out, int out_size, void* d_ws, size_t ws_size,
                              hipStream_t stream) {
    const float* x  = (const float*)d_in[0];
    const float* Wg = (const float*)d_in[1];
    const float* We = (const float*)d_in[2];
    float* out = (float*)d_out;
    float* ws  = (float*)d_ws;

    float* wfrag = ws;
    float* part  = ws + P_OFF;
    float* sums  = ws + SUM_OFF;
    int*   cnt   = (int*)(ws + CNT_OFF);
    int4*  list  = (int4*)(ws + LIST_OFF);

    moe_prep<<<64 * NT2, 64, 0, stream>>>(Wg, We, wfrag, sums, cnt);
    moe_gemm<<<(T_TOKENS / BM) * KS, 512, 0, stream>>>(x, wfrag, part);
    moe_epi<<<T_TOKENS / 32, 256, 0, stream>>>(part, out, sums, cnt, list);
    moe_fix<<<1024, 256, 0, stream>>>(x, Wg, We, out, sums, cnt, list);
    moe_finalize<<<1, 64, 0, stream>>>(sums, out);
}